// Round 10
// baseline (22472.119 us; speedup 1.0000x reference)
//
#include <hip/hip_runtime.h>

#define BB   256
#define LAT  256
#define CND  64
#define HID  1024
#define OUTD 128
#define TLEN 512
#define GIN  192
#define G4   4096

typedef _Float16 f16x8 __attribute__((ext_vector_type(8)));
typedef float    f32x4 __attribute__((ext_vector_type(4)));

#define MFMA16(A,B,C) __builtin_amdgcn_mfma_f32_16x16x32_f16((A),(B),(C),0,0,0)

__device__ __forceinline__ float fsig(float x) {
  return 1.0f / (1.0f + exp2f(-1.4426950408889634f * x));
}
__device__ __forceinline__ float ftanh_(float x) {
  return 2.0f / (1.0f + exp2f(2.8853900817779268f * (-x))) - 1.0f;
}

// ---- device-coherent (MALL) access: per-instruction bypass, no cache-wide ops ----
__device__ __forceinline__ f16x8 ldg_sc_h8(const void* p) {
  f16x8 v;
  asm volatile("global_load_dwordx4 %0, %1, off sc0 sc1" : "=v"(v) : "v"(p));
  return v;
}
__device__ __forceinline__ void stg_sc_h(void* p, _Float16 v) {
  unsigned u = (unsigned)__builtin_bit_cast(unsigned short, v);
  asm volatile("global_store_short %0, %1, off sc0 sc1" :: "v"(p), "v"(u) : "memory");
}
__device__ __forceinline__ void stg_sc_f32(void* p, float v) {
  asm volatile("global_store_dword %0, %1, off sc0 sc1" :: "v"(p), "v"(v) : "memory");
}

template<int N> __device__ __forceinline__ void waitvm() {
  if constexpr (N == 3)      asm volatile("s_waitcnt vmcnt(3)" ::: "memory");
  else if constexpr (N == 2) asm volatile("s_waitcnt vmcnt(2)" ::: "memory");
  else if constexpr (N == 1) asm volatile("s_waitcnt vmcnt(1)" ::: "memory");
  else                       asm volatile("s_waitcnt vmcnt(0)" ::: "memory");
  __builtin_amdgcn_sched_barrier(0);
}
#define LDSBAR() { asm volatile("s_waitcnt lgkmcnt(0)" ::: "memory"); \
                   __builtin_amdgcn_s_barrier(); \
                   __builtin_amdgcn_sched_barrier(0); }

// ---------------- prep kernels ----------------

__global__ void prep_init(const float* __restrict__ lat,
                          const float* __restrict__ Wh, const float* __restrict__ bh,
                          const float* __restrict__ Wc, const float* __restrict__ bc,
                          const float* __restrict__ Ws, const float* __restrict__ bs,
                          float* __restrict__ h0, _Float16* __restrict__ hF,
                          float* __restrict__ c0, float* __restrict__ x0)
{
  __shared__ float lat_s[8][LAT];
  int tid = threadIdx.x;
  int b0 = blockIdx.y * 8;
  for (int bb = 0; bb < 8; ++bb)
    lat_s[bb][tid] = lat[(size_t)(b0 + bb) * LAT + tid];
  __syncthreads();
  int col = blockIdx.x * 256 + tid;
  if (col >= 2 * HID + OUTD) return;
  const float* wr; float bias; int kind; int cc;
  if (col < HID)            { cc = col;           wr = Wh + (size_t)cc * LAT; bias = bh[cc]; kind = 0; }
  else if (col < 2 * HID)   { cc = col - HID;     wr = Wc + (size_t)cc * LAT; bias = bc[cc]; kind = 1; }
  else                      { cc = col - 2 * HID; wr = Ws + (size_t)cc * LAT; bias = bs[cc]; kind = 2; }
  float acc[8];
#pragma unroll
  for (int bb = 0; bb < 8; ++bb) acc[bb] = bias;
  for (int k = 0; k < LAT; ++k) {
    float wv = wr[k];
#pragma unroll
    for (int bb = 0; bb < 8; ++bb) acc[bb] += lat_s[bb][k] * wv;
  }
  for (int bb = 0; bb < 8; ++bb) {
    int b = b0 + bb;
    if (kind == 0) {
      float v = acc[bb];
      h0[(size_t)b*HID + cc] = v;
      hF[(size_t)b*HID + cc] = (_Float16)v;
    }
    else if (kind == 1) { c0[(size_t)b*HID + cc] = acc[bb]; }
    else                { x0[(size_t)b*OUTD + cc] = acc[bb]; }
  }
}

__global__ void prep_d(const float* __restrict__ h0, const float* __restrict__ Wout,
                       const float* __restrict__ bout, const float* __restrict__ x0,
                       float* __restrict__ d)
{
  int t = blockIdx.x * 256 + threadIdx.x;
  int b = t >> 7, o = t & 127;
  const float* wr = Wout + (size_t)o * HID;
  const float* hr = h0 + (size_t)b * HID;
  float acc = bout[o];
  for (int k = 0; k < HID; ++k) acc += hr[k] * wr[k];
  d[t] = x0[t] - acc;
}

__global__ void prep_weff(const float* __restrict__ Whh, const float* __restrict__ Wih,
                          const float* __restrict__ Wout, _Float16* __restrict__ WeffH)
{
  int k = blockIdx.x * 256 + threadIdx.x;
  int n0 = blockIdx.y * 16;
  float acc[16];
#pragma unroll
  for (int nn = 0; nn < 16; ++nn) acc[nn] = Whh[(size_t)(n0 + nn) * HID + k];
  for (int j = 0; j < OUTD; ++j) {
    float wo = Wout[(size_t)j * HID + k];
#pragma unroll
    for (int nn = 0; nn < 16; ++nn) acc[nn] += Wih[(size_t)(n0 + nn) * GIN + j] * wo;
  }
#pragma unroll
  for (int nn = 0; nn < 16; ++nn)
    WeffH[(size_t)(n0 + nn) * HID + k] = (_Float16)acc[nn];
}

__global__ void prep_wob(const float* __restrict__ Wout, _Float16* __restrict__ Wob) {
  int t = blockIdx.x * 256 + threadIdx.x;
  Wob[t] = (_Float16)Wout[t];
}

__global__ void prep_bias(const float* __restrict__ cond, const float* __restrict__ Wih,
                          const float* __restrict__ bih, const float* __restrict__ bhh,
                          const float* __restrict__ bout, const float* __restrict__ d,
                          float* __restrict__ biasR, float* __restrict__ biasS)
{
  __shared__ float cond_s[8][CND];
  __shared__ float d_s[8][OUTD];
  int tid = threadIdx.x;
  int b0 = blockIdx.y * 8;
  for (int qq = 0; qq < 2; ++qq) {
    int idx = qq * 256 + tid;
    cond_s[idx >> 6][idx & 63] = cond[(size_t)(b0 + (idx >> 6)) * CND + (idx & 63)];
  }
  for (int qq = 0; qq < 4; ++qq) {
    int idx = qq * 256 + tid;
    d_s[idx >> 7][idx & 127] = d[(size_t)(b0 + (idx >> 7)) * OUTD + (idx & 127)];
  }
  __syncthreads();
  int n = blockIdx.x * 256 + tid;
  const float* wi = Wih + (size_t)n * GIN;
  float base = bih[n] + bhh[n];
  float aR[8], aS[8];
#pragma unroll
  for (int bb = 0; bb < 8; ++bb) { aR[bb] = 0.f; aS[bb] = 0.f; }
  for (int c = 0; c < CND; ++c) {
    float wv = wi[OUTD + c];
#pragma unroll
    for (int bb = 0; bb < 8; ++bb) aR[bb] += cond_s[bb][c] * wv;
  }
  for (int o = 0; o < OUTD; ++o) {
    float wv = wi[o];
    float bo = bout[o];
#pragma unroll
    for (int bb = 0; bb < 8; ++bb) { aR[bb] += bo * wv; aS[bb] += d_s[bb][o] * wv; }
  }
  for (int bb = 0; bb < 8; ++bb) {
    size_t idx = (size_t)(b0 + bb) * G4 + n;
    biasR[idx] = base + aR[bb];
    biasS[idx] = base + aR[bb] + aS[bb];
  }
}

// ---------------- main persistent kernel ----------------
// Grid: 1024 wgs = 16 mt (16 batch rows) x 64 nt (16 cols). Block = 4 waves, one GATE
// per wave (i,f,g,o). 4 blocks/CU -> 4 waves/SIMD (latency hiding). All 4 waves share
// the LDS-staged h tile. Gate-z exchange via LDS; wave0 owns cell state, wave3 owns y.

__global__ __launch_bounds__(256, 4)
void lstm_main(_Float16* hF, const float* __restrict__ c0g,
               const float* __restrict__ biasR, const float* __restrict__ biasS,
               const _Float16* __restrict__ WeffH, const _Float16* __restrict__ Wob,
               const float* __restrict__ bout, const int* __restrict__ len,
               float* __restrict__ out, unsigned* flags)
{
  __shared__ __align__(16) char lds[17408 + 3264 + 64];  // 2 h-bufs (16x272) + z_s 3x16x17 f32
  float* z_s = (float*)(lds + 17408);
  const int wg = blockIdx.x;
  const int xcd = wg & 7, slot = wg >> 3;
  const int mt = slot & 15, q = slot >> 4;
  const int nt = q * 8 + xcd;                 // W-slice (1MB/XCD) stays in this XCD's L2
  const int tid = threadIdx.x;
  const int g = tid >> 6, lane = tid & 63;
  const int l15 = lane & 15, lh = lane >> 4;
  const int rbase = mt * 16;
  const bool cellwave = (g == 0);
  const bool ywave = (g == 3) && (nt < 8);
  const int oy = ywave ? nt * 16 + l15 : 0;
  const float bo = ywave ? bout[oy] : 0.0f;

  // W base pointer for MY gate (cached loads; L2-resident)
  const char* wb = (const char*)(WeffH + ((size_t)(g * HID + nt * 16 + l15)) * HID + lh * 8);
  const char* wy = (const char*)(Wob + (size_t)oy * HID + lh * 8);

  float c[4]; int mylen[4]; float biasRv[4];
#pragma unroll
  for (int r = 0; r < 4; ++r) {
    int row = rbase + lh * 4 + r;
    mylen[r] = len[row];
    biasRv[r] = biasR[(size_t)row * G4 + g * HID + nt * 16 + l15];
    c[r] = cellwave ? c0g[(size_t)row * HID + nt * 16 + l15] : 0.0f;
  }

  // staging: thread -> (row tid>>4, 16B-quad tid&15)
  const int srow = tid >> 4, sc16 = tid & 15;
  const _Float16* stg_g = hF + (size_t)(rbase + srow) * HID + sc16 * 8;
  const int stg_l = srow * 272 + sc16 * 16;
  const int rdoff = l15 * 272 + lh * 16;
  _Float16* hb[4];
#pragma unroll
  for (int r = 0; r < 4; ++r)
    hb[r] = hF + (size_t)(rbase + lh * 4 + r) * HID + nt * 16 + l15;

  unsigned* const myflag = flags + ((size_t)(mt * 64 + nt)) * 64;   // 256B lines
  const unsigned* const flrow = flags + ((size_t)mt * 64) * 64;

  f32x4 acc, accy;
  f16x8 pfb[4];

  for (int t = 0; t < TLEN; ++t) {
    const size_t pin  = (size_t)(t & 1) * (BB * HID);
    const size_t pout = (size_t)((t + 1) & 1) * (BB * HID);

    // ---- wait for all 64 producers of my mt (every wave polls; lane -> nt) ----
    if (t > 0) {
      const unsigned* fl = flrow + (size_t)lane * 64;
      long guard = 0;
      for (;;) {
        unsigned v = __hip_atomic_load(fl, __ATOMIC_RELAXED, __HIP_MEMORY_SCOPE_AGENT);
        if (__ballot(v >= (unsigned)t) == ~0ull) break;
        if (++guard > 2000000L) break;   // tripwire: fail visibly, don't hang
        __builtin_amdgcn_s_sleep(1);
      }
      __builtin_amdgcn_sched_barrier(0);
    }

    auto issue = [&](int K) {
      pfb[K & 3] = ldg_sc_h8(stg_g + pin + K * 128);
    };
    auto dswr = [&](int K) {
      *(f16x8*)(lds + (K & 1) * 8704 + stg_l) = pfb[K & 3];
    };
    auto comp = [&](int K) {
      const char* Bb = lds + (K & 1) * 8704;
#pragma unroll
      for (int kc = 0; kc < 4; ++kc) {
        f16x8 a = *(const f16x8*)(Bb + rdoff + kc * 64);
        const int wo = K * 256 + kc * 64;
        f16x8 wv = *(const f16x8*)(wb + wo);
        acc = MFMA16(a, wv, acc);
        if (ywave) {
          f16x8 wyv = *(const f16x8*)(wy + wo);
          accy = MFMA16(a, wyv, accy);
        }
      }
    };

    // accumulator init
#pragma unroll
    for (int r = 0; r < 4; ++r) {
      acc[r] = biasRv[r];
      accy[r] = bo;
    }
    if (t == 0) {
#pragma unroll
      for (int r = 0; r < 4; ++r)
        acc[r] = biasS[(size_t)(rbase + lh * 4 + r) * G4 + g * HID + nt * 16 + l15];
    }

    issue(0); issue(1); issue(2); issue(3);
    __builtin_amdgcn_sched_barrier(0);

    waitvm<3>(); dswr(0); LDSBAR(); issue(4); __builtin_amdgcn_sched_barrier(0); comp(0);
    waitvm<3>(); dswr(1); LDSBAR(); issue(5); __builtin_amdgcn_sched_barrier(0); comp(1);
    waitvm<3>(); dswr(2); LDSBAR(); issue(6); __builtin_amdgcn_sched_barrier(0); comp(2);
    waitvm<3>(); dswr(3); LDSBAR(); issue(7); __builtin_amdgcn_sched_barrier(0); comp(3);
    waitvm<3>(); dswr(4); LDSBAR(); comp(4);
    waitvm<2>(); dswr(5); LDSBAR(); comp(5);
    waitvm<1>(); dswr(6); LDSBAR(); comp(6);
    waitvm<0>(); dswr(7); LDSBAR(); comp(7);

    // ---- gate exchange: waves 1..3 publish z to LDS ----
    if (g != 0) {
#pragma unroll
      for (int r = 0; r < 4; ++r)
        z_s[(g - 1) * 272 + (lh * 4 + r) * 17 + l15] = acc[r];
    }
    LDSBAR();

    if (cellwave) {
#pragma unroll
      for (int r = 0; r < 4; ++r) {
        int zo_i = (lh * 4 + r) * 17 + l15;
        float zi = acc[r];
        float zf = z_s[zo_i];
        float zg = z_s[272 + zo_i];
        float zo = z_s[544 + zo_i];
        float ig = fsig(zi);
        float fg = fsig(zf);
        float gg = ftanh_(zg);
        float og = fsig(zo);
        float cn = fg * c[r] + ig * gg;
        c[r] = cn;
        float hn = og * ftanh_(cn);
        stg_sc_h(hb[r] + pout, (_Float16)hn);
      }
      asm volatile("s_waitcnt vmcnt(0)" ::: "memory");
      if (lane == 0)
        __hip_atomic_store(myflag, (unsigned)(t + 1), __ATOMIC_RELAXED, __HIP_MEMORY_SCOPE_AGENT);
    }
    if (ywave && t > 0) {
      int tb = t - 1;
#pragma unroll
      for (int r = 0; r < 4; ++r) {
        float v = (tb < mylen[r]) ? accy[r] : 0.0f;
        stg_sc_f32(out + ((size_t)(rbase + lh * 4 + r) * TLEN + tb) * OUTD + oy, v);
      }
    }
  }

  // epilogue: y_{511} = Wout*h_512 + bout  (h_512 in parity-0 buffer)
  if (ywave) {
    {
      const unsigned* fl = flrow + (size_t)lane * 64;
      long guard = 0;
      for (;;) {
        unsigned v = __hip_atomic_load(fl, __ATOMIC_RELAXED, __HIP_MEMORY_SCOPE_AGENT);
        if (__ballot(v >= (unsigned)TLEN) == ~0ull) break;
        if (++guard > 2000000L) break;
        __builtin_amdgcn_s_sleep(1);
      }
      __builtin_amdgcn_sched_barrier(0);
    }
    f32x4 aM;
#pragma unroll
    for (int r = 0; r < 4; ++r) aM[r] = bo;
    const _Float16* ebase = hF + (size_t)(rbase + l15) * HID + lh * 8;
    for (int cc = 0; cc < 8; ++cc) {
      f16x8 e[4];
#pragma unroll
      for (int kc = 0; kc < 4; ++kc)
        e[kc] = ldg_sc_h8(ebase + cc * 128 + kc * 32);
      waitvm<0>();
#pragma unroll
      for (int kc = 0; kc < 4; ++kc) {
        f16x8 wyv = *(const f16x8*)(wy + cc * 256 + kc * 64);
        aM = MFMA16(e[kc], wyv, aM);
      }
    }
#pragma unroll
    for (int r = 0; r < 4; ++r) {
      float v = ((TLEN - 1) < mylen[r]) ? aM[r] : 0.0f;
      stg_sc_f32(out + ((size_t)(rbase + lh * 4 + r) * TLEN + (TLEN - 1)) * OUTD + oy, v);
    }
  }
}

// ---------------- host ----------------

extern "C" void kernel_launch(void* const* d_in, const int* in_sizes, int n_in,
                              void* d_out, int out_size, void* d_ws, size_t ws_size,
                              hipStream_t stream)
{
  const float* lat  = (const float*)d_in[0];
  const float* cond = (const float*)d_in[1];
  const int*   len  = (const int*)d_in[2];
  const float* Wh   = (const float*)d_in[3];
  const float* bh   = (const float*)d_in[4];
  const float* Wc   = (const float*)d_in[5];
  const float* bc   = (const float*)d_in[6];
  const float* Ws   = (const float*)d_in[7];
  const float* bs   = (const float*)d_in[8];
  const float* Wih  = (const float*)d_in[9];
  const float* Whh  = (const float*)d_in[10];
  const float* bih  = (const float*)d_in[11];
  const float* bhh  = (const float*)d_in[12];
  const float* Wout = (const float*)d_in[13];
  const float* bout = (const float*)d_in[14];
  float* out = (float*)d_out;

  char* ws = (char*)d_ws;
  size_t off = 0;
  auto alloc = [&](size_t bytes) -> void* {
    void* p = ws + off;
    off += (bytes + 255) & ~(size_t)255;
    return p;
  };
  _Float16* hF    = (_Float16*)alloc((size_t)2 * BB * HID * 2);
  float*    c0    = (float*)alloc((size_t)BB * HID * 4);
  float*    h0    = (float*)alloc((size_t)BB * HID * 4);
  float*    x0    = (float*)alloc((size_t)BB * OUTD * 4);
  float*    dxy   = (float*)alloc((size_t)BB * OUTD * 4);
  _Float16* Wob   = (_Float16*)alloc((size_t)OUTD * HID * 2);
  _Float16* WeffH = (_Float16*)alloc((size_t)G4 * HID * 2);
  float*    biasR = (float*)alloc((size_t)BB * G4 * 4);
  float*    biasS = (float*)alloc((size_t)BB * G4 * 4);
  unsigned* flags = (unsigned*)alloc((size_t)16 * 64 * 64 * 4);   // [mt][nt] 256B lines
  if (off > ws_size) return;

  hipMemsetAsync(flags, 0, (size_t)16 * 64 * 64 * 4, stream);

  prep_init<<<dim3(9, 32),   256, 0, stream>>>(lat, Wh, bh, Wc, bc, Ws, bs, h0, hF, c0, x0);
  prep_weff<<<dim3(4, 256),  256, 0, stream>>>(Whh, Wih, Wout, WeffH);
  prep_wob <<<dim3(512),     256, 0, stream>>>(Wout, Wob);
  prep_d   <<<dim3(128),     256, 0, stream>>>(h0, Wout, bout, x0, dxy);
  prep_bias<<<dim3(16, 32),  256, 0, stream>>>(cond, Wih, bih, bhh, bout, dxy, biasR, biasS);
  lstm_main<<<dim3(1024),    256, 0, stream>>>(hF, c0, biasR, biasS, WeffH, Wob, bout, len, out, flags);
}

// Round 13
// 11351.446 us; speedup vs baseline: 1.9797x; 1.9797x over previous
//
#include <hip/hip_runtime.h>

#define BB   256
#define LAT  256
#define CND  64
#define HID  1024
#define OUTD 128
#define TLEN 512
#define GIN  192
#define G4   4096

typedef _Float16 f16x8 __attribute__((ext_vector_type(8)));
typedef float    f32x4 __attribute__((ext_vector_type(4)));

#define MFMA16(A,B,C) __builtin_amdgcn_mfma_f32_16x16x32_f16((A),(B),(C),0,0,0)

__device__ __forceinline__ float fsig(float x) {
  return 1.0f / (1.0f + exp2f(-1.4426950408889634f * x));
}
__device__ __forceinline__ float ftanh_(float x) {
  return 2.0f / (1.0f + exp2f(2.8853900817779268f * (-x))) - 1.0f;
}

// ---- device-coherent (MALL) access: per-instruction bypass, no cache-wide ops ----
__device__ __forceinline__ f16x8 ldg_sc_h8(const void* p) {
  f16x8 v;
  asm volatile("global_load_dwordx4 %0, %1, off sc0 sc1" : "=v"(v) : "v"(p));
  return v;
}
__device__ __forceinline__ void stg_sc_h(void* p, _Float16 v) {
  unsigned u = (unsigned)__builtin_bit_cast(unsigned short, v);
  asm volatile("global_store_short %0, %1, off sc0 sc1" :: "v"(p), "v"(u) : "memory");
}
__device__ __forceinline__ void stg_sc_f32(void* p, float v) {
  asm volatile("global_store_dword %0, %1, off sc0 sc1" :: "v"(p), "v"(v) : "memory");
}

template<int N> __device__ __forceinline__ void waitvm() {
  if constexpr (N == 8) asm volatile("s_waitcnt vmcnt(8)" ::: "memory");
  else                  asm volatile("s_waitcnt vmcnt(0)" ::: "memory");
  __builtin_amdgcn_sched_barrier(0);
}
#define LDSBAR() { asm volatile("s_waitcnt lgkmcnt(0)" ::: "memory"); \
                   __builtin_amdgcn_s_barrier(); \
                   __builtin_amdgcn_sched_barrier(0); }

// ---------------- prep kernels ----------------

__global__ void prep_init(const float* __restrict__ lat,
                          const float* __restrict__ Wh, const float* __restrict__ bh,
                          const float* __restrict__ Wc, const float* __restrict__ bc,
                          const float* __restrict__ Ws, const float* __restrict__ bs,
                          float* __restrict__ h0, _Float16* __restrict__ hF,
                          float* __restrict__ c0, float* __restrict__ x0)
{
  __shared__ float lat_s[8][LAT];
  int tid = threadIdx.x;
  int b0 = blockIdx.y * 8;
  for (int bb = 0; bb < 8; ++bb)
    lat_s[bb][tid] = lat[(size_t)(b0 + bb) * LAT + tid];
  __syncthreads();
  int col = blockIdx.x * 256 + tid;
  if (col >= 2 * HID + OUTD) return;
  const float* wr; float bias; int kind; int cc;
  if (col < HID)            { cc = col;           wr = Wh + (size_t)cc * LAT; bias = bh[cc]; kind = 0; }
  else if (col < 2 * HID)   { cc = col - HID;     wr = Wc + (size_t)cc * LAT; bias = bc[cc]; kind = 1; }
  else                      { cc = col - 2 * HID; wr = Ws + (size_t)cc * LAT; bias = bs[cc]; kind = 2; }
  float acc[8];
#pragma unroll
  for (int bb = 0; bb < 8; ++bb) acc[bb] = bias;
  for (int k = 0; k < LAT; ++k) {
    float wv = wr[k];
#pragma unroll
    for (int bb = 0; bb < 8; ++bb) acc[bb] += lat_s[bb][k] * wv;
  }
  for (int bb = 0; bb < 8; ++bb) {
    int b = b0 + bb;
    if (kind == 0) {
      float v = acc[bb];
      h0[(size_t)b*HID + cc] = v;
      hF[(size_t)b*HID + cc] = (_Float16)v;
    }
    else if (kind == 1) { c0[(size_t)b*HID + cc] = acc[bb]; }
    else                { x0[(size_t)b*OUTD + cc] = acc[bb]; }
  }
}

__global__ void prep_d(const float* __restrict__ h0, const float* __restrict__ Wout,
                       const float* __restrict__ bout, const float* __restrict__ x0,
                       float* __restrict__ d)
{
  int t = blockIdx.x * 256 + threadIdx.x;
  int b = t >> 7, o = t & 127;
  const float* wr = Wout + (size_t)o * HID;
  const float* hr = h0 + (size_t)b * HID;
  float acc = bout[o];
  for (int k = 0; k < HID; ++k) acc += hr[k] * wr[k];
  d[t] = x0[t] - acc;
}

__global__ void prep_weff(const float* __restrict__ Whh, const float* __restrict__ Wih,
                          const float* __restrict__ Wout, _Float16* __restrict__ WeffH)
{
  int k = blockIdx.x * 256 + threadIdx.x;
  int n0 = blockIdx.y * 16;
  float acc[16];
#pragma unroll
  for (int nn = 0; nn < 16; ++nn) acc[nn] = Whh[(size_t)(n0 + nn) * HID + k];
  for (int j = 0; j < OUTD; ++j) {
    float wo = Wout[(size_t)j * HID + k];
#pragma unroll
    for (int nn = 0; nn < 16; ++nn) acc[nn] += Wih[(size_t)(n0 + nn) * GIN + j] * wo;
  }
#pragma unroll
  for (int nn = 0; nn < 16; ++nn)
    WeffH[(size_t)(n0 + nn) * HID + k] = (_Float16)acc[nn];
}

__global__ void prep_wob(const float* __restrict__ Wout, _Float16* __restrict__ Wob) {
  int t = blockIdx.x * 256 + threadIdx.x;
  Wob[t] = (_Float16)Wout[t];
}

__global__ void prep_bias(const float* __restrict__ cond, const float* __restrict__ Wih,
                          const float* __restrict__ bih, const float* __restrict__ bhh,
                          const float* __restrict__ bout, const float* __restrict__ d,
                          float* __restrict__ biasR, float* __restrict__ biasS)
{
  __shared__ float cond_s[8][CND];
  __shared__ float d_s[8][OUTD];
  int tid = threadIdx.x;
  int b0 = blockIdx.y * 8;
  for (int qq = 0; qq < 2; ++qq) {
    int idx = qq * 256 + tid;
    cond_s[idx >> 6][idx & 63] = cond[(size_t)(b0 + (idx >> 6)) * CND + (idx & 63)];
  }
  for (int qq = 0; qq < 4; ++qq) {
    int idx = qq * 256 + tid;
    d_s[idx >> 7][idx & 127] = d[(size_t)(b0 + (idx >> 7)) * OUTD + (idx & 127)];
  }
  __syncthreads();
  int n = blockIdx.x * 256 + tid;
  const float* wi = Wih + (size_t)n * GIN;
  float base = bih[n] + bhh[n];
  float aR[8], aS[8];
#pragma unroll
  for (int bb = 0; bb < 8; ++bb) { aR[bb] = 0.f; aS[bb] = 0.f; }
  for (int c = 0; c < CND; ++c) {
    float wv = wi[OUTD + c];
#pragma unroll
    for (int bb = 0; bb < 8; ++bb) aR[bb] += cond_s[bb][c] * wv;
  }
  for (int o = 0; o < OUTD; ++o) {
    float wv = wi[o];
    float bo = bout[o];
#pragma unroll
    for (int bb = 0; bb < 8; ++bb) { aR[bb] += bo * wv; aS[bb] += d_s[bb][o] * wv; }
  }
  for (int bb = 0; bb < 8; ++bb) {
    size_t idx = (size_t)(b0 + bb) * G4 + n;
    biasR[idx] = base + aR[bb];
    biasS[idx] = base + aR[bb] + aS[bb];
  }
}

// ---------------- main persistent kernel ----------------
// r9 structure (best passing), W single plane (r10-validated numerics),
// 4 chunks of 256 k-cols (half the barriers/vm-waits of r9).
// Grid: 256 wgs = 4 mt (64-batch tiles) x 64 nt (16 gate/h cols). Per-mt barrier.

__global__ __launch_bounds__(256, 1)
void lstm_main(_Float16* hF, const float* __restrict__ c0g,
               const float* __restrict__ biasR, const float* __restrict__ biasS,
               const _Float16* __restrict__ WeffH, const _Float16* __restrict__ Wob,
               const float* __restrict__ bout, const int* __restrict__ len,
               float* __restrict__ out, unsigned* bar)
{
  __shared__ __align__(16) char lds[67584];   // 2 bufs x 33792 (64 rows x 528B: 512 data + 16 pad)
  const int wg = blockIdx.x;
  const int xcd = wg & 7, slot = wg >> 3;
  const int q = slot >> 2, mt = slot & 3;
  const int nt = q * 8 + xcd;                 // W-slice stays in this XCD's L2
  const int tid = threadIdx.x;
  const int w = tid >> 6, lane = tid & 63;
  const int l15 = lane & 15, lh = lane >> 4;
  const int rowA = w * 16 + l15;
  const int bD0 = mt * 64 + w * 16 + lh * 4;
  const int j = nt * 16 + l15;
  const bool doy = (nt < 8);
  const int oy = doy ? nt * 16 + l15 : 0;
  const float bo = doy ? bout[oy] : 0.0f;

  // weight base pointers (cached loads; L2-resident, never invalidated)
  const char* wb[4];
#pragma unroll
  for (int g = 0; g < 4; ++g)
    wb[g] = (const char*)(WeffH + ((size_t)(g * HID + nt * 16 + l15)) * HID + lh * 8);
  const char* wbY = (const char*)(Wob + (size_t)oy * HID + lh * 8);

  float c[4]; int mylen[4]; float biasRv[16];
#pragma unroll
  for (int r = 0; r < 4; ++r) {
    c[r] = c0g[(size_t)(bD0 + r) * HID + j];
    mylen[r] = len[bD0 + r];
    size_t bi = (size_t)(bD0 + r) * G4 + nt * 16 + l15;
#pragma unroll
    for (int g = 0; g < 4; ++g) biasRv[r * 4 + g] = biasR[bi + (size_t)g * HID];
  }

  // staging-slot addressing: slot s = i*256+tid -> row s>>5 (0..63), 16B-quad s&31
  const _Float16* cb0[8];
  int rc8[8];
#pragma unroll
  for (int i = 0; i < 8; ++i) {
    int s = i * 256 + tid;
    int r = s >> 5, cc = s & 31;
    cb0[i] = hF + ((size_t)(mt * 64 + r) * HID + cc * 8);
    rc8[i] = r * 528 + cc * 16;
  }
  const int rdoff = rowA * 528 + lh * 16;
  _Float16* hb0[4];
#pragma unroll
  for (int r = 0; r < 4; ++r) hb0[r] = hF + ((size_t)(bD0 + r) * HID + j);

  unsigned* const myarr = bar + (size_t)(mt * 8 + xcd) * 64;   // 256B-spaced lines

  f32x4 accM[4], accyM;
  f16x8 pfb[2][8];

  for (int t = 0; t < TLEN; ++t) {
    const size_t parin  = (size_t)(t & 1) * (BB * HID);
    const size_t parout = (size_t)((t + 1) & 1) * (BB * HID);

    auto issue = [&](int K) {
#pragma unroll
      for (int i = 0; i < 8; ++i)
        pfb[K & 1][i] = ldg_sc_h8(cb0[i] + parin + K * 256);
    };
    auto dswr = [&](int K) {
      char* Bb = lds + (K & 1) * 33792;
#pragma unroll
      for (int i = 0; i < 8; ++i)
        *(f16x8*)(Bb + rc8[i]) = pfb[K & 1][i];
    };
    auto comp = [&](int K) {
      const char* Bb = lds + (K & 1) * 33792;
#pragma unroll
      for (int kc = 0; kc < 8; ++kc) {
        f16x8 aH = *(const f16x8*)(Bb + rdoff + kc * 64);
        const int wo = K * 512 + kc * 64;
#pragma unroll
        for (int g = 0; g < 4; ++g) {
          f16x8 wH = *(const f16x8*)(wb[g] + wo);
          accM[g] = MFMA16(aH, wH, accM[g]);
        }
        if (doy) {
          f16x8 wy = *(const f16x8*)(wbY + wo);
          accyM = MFMA16(aH, wy, accyM);
        }
      }
    };

    // prefetch 2 chunks deep (16 loads in flight)
    issue(0); issue(1);

    // accumulator init
#pragma unroll
    for (int r = 0; r < 4; ++r) {
#pragma unroll
      for (int g = 0; g < 4; ++g) accM[g][r] = biasRv[r * 4 + g];
      accyM[r] = bo;
    }
    if (t == 0) {
#pragma unroll
      for (int r = 0; r < 4; ++r) {
        size_t bi = (size_t)(bD0 + r) * G4 + nt * 16 + l15;
#pragma unroll
        for (int g = 0; g < 4; ++g) accM[g][r] = biasS[bi + (size_t)g * HID];
      }
    }

    waitvm<8>(); dswr(0); LDSBAR(); issue(2); comp(0);
    waitvm<8>(); dswr(1); LDSBAR(); issue(3); comp(1);
    waitvm<8>(); dswr(2); LDSBAR(); comp(2);
    waitvm<0>(); dswr(3); LDSBAR(); comp(3);

    // LSTM cell (fp32), f16 h_{t+1} store
#pragma unroll
    for (int r = 0; r < 4; ++r) {
      float ig = fsig(accM[0][r]);
      float fg = fsig(accM[1][r]);
      float gg = ftanh_(accM[2][r]);
      float og = fsig(accM[3][r]);
      float cn = fg * c[r] + ig * gg;
      c[r] = cn;
      float hn = og * ftanh_(cn);
      stg_sc_h(hb0[r] + parout, (_Float16)hn);
    }
    if (doy && t > 0) {
      int tb = t - 1;
#pragma unroll
      for (int r = 0; r < 4; ++r) {
        float v = (tb < mylen[r]) ? accyM[r] : 0.0f;
        stg_sc_f32(out + ((size_t)(bD0 + r) * TLEN + tb) * OUTD + oy, v);
      }
    }

    // ---- per-mt barrier: 8 spread arrival lines + wave-parallel poll ----
    asm volatile("s_waitcnt vmcnt(0)" ::: "memory");
    __syncthreads();
    if (tid < 64) {
      if (tid == 0)
        __hip_atomic_fetch_add(myarr, 1u, __ATOMIC_RELAXED, __HIP_MEMORY_SCOPE_AGENT);
      if (t < TLEN - 1 || doy) {
        unsigned tgt = 8u * (unsigned)(t + 1);
        long guard = 0;
        for (;;) {
          unsigned v = tgt;
          if (tid < 8)
            v = __hip_atomic_load(bar + (size_t)(mt * 8 + tid) * 64,
                                  __ATOMIC_RELAXED, __HIP_MEMORY_SCOPE_AGENT);
          if (__ballot(v >= tgt) == ~0ull) break;
          if (++guard > 2000000L) break;   // tripwire: fail visibly, don't hang
          __builtin_amdgcn_s_sleep(2);
        }
      }
    }
    __syncthreads();
  }

  // epilogue: y_{511} = Wout*h_512 + bout   (h_512 in parity-0 buffer)
  if (doy) {
    f32x4 aM;
#pragma unroll
    for (int r = 0; r < 4; ++r) aM[r] = bo;
    const _Float16* ebase = hF + (size_t)(mt * 64 + rowA) * HID + lh * 8;
    for (int b = 0; b < 8; ++b) {
      f16x8 e[4];
#pragma unroll
      for (int kc = 0; kc < 4; ++kc)
        e[kc] = ldg_sc_h8(ebase + b * 128 + kc * 32);
      asm volatile("s_waitcnt vmcnt(0)" ::: "memory");
      __builtin_amdgcn_sched_barrier(0);
#pragma unroll
      for (int kc = 0; kc < 4; ++kc) {
        f16x8 wy = *(const f16x8*)(wbY + b * 256 + kc * 64);
        aM = MFMA16(e[kc], wy, aM);
      }
    }
#pragma unroll
    for (int r = 0; r < 4; ++r) {
      float v = ((TLEN - 1) < mylen[r]) ? aM[r] : 0.0f;
      stg_sc_f32(out + ((size_t)(bD0 + r) * TLEN + (TLEN - 1)) * OUTD + oy, v);
    }
  }
}

// ---------------- host ----------------

extern "C" void kernel_launch(void* const* d_in, const int* in_sizes, int n_in,
                              void* d_out, int out_size, void* d_ws, size_t ws_size,
                              hipStream_t stream)
{
  const float* lat  = (const float*)d_in[0];
  const float* cond = (const float*)d_in[1];
  const int*   len  = (const int*)d_in[2];
  const float* Wh   = (const float*)d_in[3];
  const float* bh   = (const float*)d_in[4];
  const float* Wc   = (const float*)d_in[5];
  const float* bc   = (const float*)d_in[6];
  const float* Ws   = (const float*)d_in[7];
  const float* bs   = (const float*)d_in[8];
  const float* Wih  = (const float*)d_in[9];
  const float* Whh  = (const float*)d_in[10];
  const float* bih  = (const float*)d_in[11];
  const float* bhh  = (const float*)d_in[12];
  const float* Wout = (const float*)d_in[13];
  const float* bout = (const float*)d_in[14];
  float* out = (float*)d_out;

  char* ws = (char*)d_ws;
  size_t off = 0;
  auto alloc = [&](size_t bytes) -> void* {
    void* p = ws + off;
    off += (bytes + 255) & ~(size_t)255;
    return p;
  };
  _Float16* hF    = (_Float16*)alloc((size_t)2 * BB * HID * 2);   // single f16 plane
  float*    c0    = (float*)alloc((size_t)BB * HID * 4);
  float*    h0    = (float*)alloc((size_t)BB * HID * 4);
  float*    x0    = (float*)alloc((size_t)BB * OUTD * 4);
  float*    dxy   = (float*)alloc((size_t)BB * OUTD * 4);
  _Float16* Wob   = (_Float16*)alloc((size_t)OUTD * HID * 2);
  _Float16* WeffH = (_Float16*)alloc((size_t)G4 * HID * 2);
  float*    biasR = (float*)alloc((size_t)BB * G4 * 4);
  float*    biasS = (float*)alloc((size_t)BB * G4 * 4);
  unsigned* bar   = (unsigned*)alloc(4 * 8 * 64 * 4);             // 32 lines, 256B apart
  if (off > ws_size) return;

  hipMemsetAsync(bar, 0, 4 * 8 * 64 * 4, stream);

  prep_init<<<dim3(9, 32),   256, 0, stream>>>(lat, Wh, bh, Wc, bc, Ws, bs, h0, hF, c0, x0);
  prep_weff<<<dim3(4, 256),  256, 0, stream>>>(Whh, Wih, Wout, WeffH);
  prep_wob <<<dim3(512),     256, 0, stream>>>(Wout, Wob);
  prep_d   <<<dim3(128),     256, 0, stream>>>(h0, Wout, bout, x0, dxy);
  prep_bias<<<dim3(16, 32),  256, 0, stream>>>(cond, Wih, bih, bhh, bout, dxy, biasR, biasS);
  lstm_main<<<dim3(256),     256, 0, stream>>>(hF, c0, biasR, biasS, WeffH, Wob, bout, len, out, bar);
}

// Round 14
// 11102.661 us; speedup vs baseline: 2.0240x; 1.0224x over previous
//
#include <hip/hip_runtime.h>

#define BB   256
#define LAT  256
#define CND  64
#define HID  1024
#define OUTD 128
#define TLEN 512
#define GIN  192
#define G4   4096

typedef _Float16 f16x8 __attribute__((ext_vector_type(8)));
typedef float    f32x4 __attribute__((ext_vector_type(4)));

#define MFMA16(A,B,C) __builtin_amdgcn_mfma_f32_16x16x32_f16((A),(B),(C),0,0,0)

__device__ __forceinline__ float fsig(float x) {
  return 1.0f / (1.0f + exp2f(-1.4426950408889634f * x));
}
__device__ __forceinline__ float ftanh_(float x) {
  return 2.0f / (1.0f + exp2f(2.8853900817779268f * (-x))) - 1.0f;
}

// ---- device-coherent (MALL) access: per-instruction bypass, no cache-wide ops ----
__device__ __forceinline__ f16x8 ldg_sc_h8(const void* p) {
  f16x8 v;
  asm volatile("global_load_dwordx4 %0, %1, off sc0 sc1" : "=v"(v) : "v"(p));
  return v;
}
__device__ __forceinline__ void stg_sc_h(void* p, _Float16 v) {
  unsigned u = (unsigned)__builtin_bit_cast(unsigned short, v);
  asm volatile("global_store_short %0, %1, off sc0 sc1" :: "v"(p), "v"(u) : "memory");
}
__device__ __forceinline__ void stg_sc_f32(void* p, float v) {
  asm volatile("global_store_dword %0, %1, off sc0 sc1" :: "v"(p), "v"(v) : "memory");
}

template<int N> __device__ __forceinline__ void waitvm() {
  if constexpr (N == 24)      asm volatile("s_waitcnt vmcnt(24)" ::: "memory");
  else if constexpr (N == 16) asm volatile("s_waitcnt vmcnt(16)" ::: "memory");
  else if constexpr (N == 8)  asm volatile("s_waitcnt vmcnt(8)"  ::: "memory");
  else                        asm volatile("s_waitcnt vmcnt(0)"  ::: "memory");
  __builtin_amdgcn_sched_barrier(0);
}
#define LDSBAR() { asm volatile("s_waitcnt lgkmcnt(0)" ::: "memory"); \
                   __builtin_amdgcn_s_barrier(); \
                   __builtin_amdgcn_sched_barrier(0); }

// ---------------- prep kernels (r13-identical) ----------------

__global__ void prep_init(const float* __restrict__ lat,
                          const float* __restrict__ Wh, const float* __restrict__ bh,
                          const float* __restrict__ Wc, const float* __restrict__ bc,
                          const float* __restrict__ Ws, const float* __restrict__ bs,
                          float* __restrict__ h0, _Float16* __restrict__ hF,
                          float* __restrict__ c0, float* __restrict__ x0)
{
  __shared__ float lat_s[8][LAT];
  int tid = threadIdx.x;
  int b0 = blockIdx.y * 8;
  for (int bb = 0; bb < 8; ++bb)
    lat_s[bb][tid] = lat[(size_t)(b0 + bb) * LAT + tid];
  __syncthreads();
  int col = blockIdx.x * 256 + tid;
  if (col >= 2 * HID + OUTD) return;
  const float* wr; float bias; int kind; int cc;
  if (col < HID)            { cc = col;           wr = Wh + (size_t)cc * LAT; bias = bh[cc]; kind = 0; }
  else if (col < 2 * HID)   { cc = col - HID;     wr = Wc + (size_t)cc * LAT; bias = bc[cc]; kind = 1; }
  else                      { cc = col - 2 * HID; wr = Ws + (size_t)cc * LAT; bias = bs[cc]; kind = 2; }
  float acc[8];
#pragma unroll
  for (int bb = 0; bb < 8; ++bb) acc[bb] = bias;
  for (int k = 0; k < LAT; ++k) {
    float wv = wr[k];
#pragma unroll
    for (int bb = 0; bb < 8; ++bb) acc[bb] += lat_s[bb][k] * wv;
  }
  for (int bb = 0; bb < 8; ++bb) {
    int b = b0 + bb;
    if (kind == 0) {
      float v = acc[bb];
      h0[(size_t)b*HID + cc] = v;
      hF[(size_t)b*HID + cc] = (_Float16)v;
    }
    else if (kind == 1) { c0[(size_t)b*HID + cc] = acc[bb]; }
    else                { x0[(size_t)b*OUTD + cc] = acc[bb]; }
  }
}

__global__ void prep_d(const float* __restrict__ h0, const float* __restrict__ Wout,
                       const float* __restrict__ bout, const float* __restrict__ x0,
                       float* __restrict__ d)
{
  int t = blockIdx.x * 256 + threadIdx.x;
  int b = t >> 7, o = t & 127;
  const float* wr = Wout + (size_t)o * HID;
  const float* hr = h0 + (size_t)b * HID;
  float acc = bout[o];
  for (int k = 0; k < HID; ++k) acc += hr[k] * wr[k];
  d[t] = x0[t] - acc;
}

__global__ void prep_weff(const float* __restrict__ Whh, const float* __restrict__ Wih,
                          const float* __restrict__ Wout, _Float16* __restrict__ WeffH)
{
  int k = blockIdx.x * 256 + threadIdx.x;
  int n0 = blockIdx.y * 16;
  float acc[16];
#pragma unroll
  for (int nn = 0; nn < 16; ++nn) acc[nn] = Whh[(size_t)(n0 + nn) * HID + k];
  for (int j = 0; j < OUTD; ++j) {
    float wo = Wout[(size_t)j * HID + k];
#pragma unroll
    for (int nn = 0; nn < 16; ++nn) acc[nn] += Wih[(size_t)(n0 + nn) * GIN + j] * wo;
  }
#pragma unroll
  for (int nn = 0; nn < 16; ++nn)
    WeffH[(size_t)(n0 + nn) * HID + k] = (_Float16)acc[nn];
}

__global__ void prep_wob(const float* __restrict__ Wout, _Float16* __restrict__ Wob) {
  int t = blockIdx.x * 256 + threadIdx.x;
  Wob[t] = (_Float16)Wout[t];
}

__global__ void prep_bias(const float* __restrict__ cond, const float* __restrict__ Wih,
                          const float* __restrict__ bih, const float* __restrict__ bhh,
                          const float* __restrict__ bout, const float* __restrict__ d,
                          float* __restrict__ biasR, float* __restrict__ biasS)
{
  __shared__ float cond_s[8][CND];
  __shared__ float d_s[8][OUTD];
  int tid = threadIdx.x;
  int b0 = blockIdx.y * 8;
  for (int qq = 0; qq < 2; ++qq) {
    int idx = qq * 256 + tid;
    cond_s[idx >> 6][idx & 63] = cond[(size_t)(b0 + (idx >> 6)) * CND + (idx & 63)];
  }
  for (int qq = 0; qq < 4; ++qq) {
    int idx = qq * 256 + tid;
    d_s[idx >> 7][idx & 127] = d[(size_t)(b0 + (idx >> 7)) * OUTD + (idx & 127)];
  }
  __syncthreads();
  int n = blockIdx.x * 256 + tid;
  const float* wi = Wih + (size_t)n * GIN;
  float base = bih[n] + bhh[n];
  float aR[8], aS[8];
#pragma unroll
  for (int bb = 0; bb < 8; ++bb) { aR[bb] = 0.f; aS[bb] = 0.f; }
  for (int c = 0; c < CND; ++c) {
    float wv = wi[OUTD + c];
#pragma unroll
    for (int bb = 0; bb < 8; ++bb) aR[bb] += cond_s[bb][c] * wv;
  }
  for (int o = 0; o < OUTD; ++o) {
    float wv = wi[o];
    float bo = bout[o];
#pragma unroll
    for (int bb = 0; bb < 8; ++bb) { aR[bb] += bo * wv; aS[bb] += d_s[bb][o] * wv; }
  }
  for (int bb = 0; bb < 8; ++bb) {
    size_t idx = (size_t)(b0 + bb) * G4 + n;
    biasR[idx] = base + aR[bb];
    biasS[idx] = base + aR[bb] + aS[bb];
  }
}

// ---------------- main persistent kernel ----------------
// r13 structure with full-step prefetch: 32 h-loads issued at once (MALL latency paid
// once/step), staged vmcnt drains into 4 LDS chunk-bufs (T2 XOR-swizzled, no pad),
// ONE LDS barrier, then 4 uninterrupted comp phases. Flag publish before y-stores.
// Grid: 256 wgs = 4 mt (64-batch tiles) x 64 nt (16 gate/h cols). Per-mt barrier.

__global__ __launch_bounds__(256, 1)
void lstm_main(_Float16* hF, const float* __restrict__ c0g,
               const float* __restrict__ biasR, const float* __restrict__ biasS,
               const _Float16* __restrict__ WeffH, const _Float16* __restrict__ Wob,
               const float* __restrict__ bout, const int* __restrict__ len,
               float* __restrict__ out, unsigned* bar)
{
  __shared__ __align__(16) char lds[131072];  // 4 chunk-bufs x 32768 (64 rows x 512B, XOR-swizzled)
  const int wg = blockIdx.x;
  const int xcd = wg & 7, slot = wg >> 3;
  const int q = slot >> 2, mt = slot & 3;
  const int nt = q * 8 + xcd;                 // W-slice stays in this XCD's L2
  const int tid = threadIdx.x;
  const int w = tid >> 6, lane = tid & 63;
  const int l15 = lane & 15, lh = lane >> 4;
  const int rowA = w * 16 + l15;
  const int bD0 = mt * 64 + w * 16 + lh * 4;
  const int j = nt * 16 + l15;
  const bool doy = (nt < 8);
  const int oy = doy ? nt * 16 + l15 : 0;
  const float bo = doy ? bout[oy] : 0.0f;

  // weight base pointers (cached loads; L2-resident, never invalidated)
  const char* wb[4];
#pragma unroll
  for (int g = 0; g < 4; ++g)
    wb[g] = (const char*)(WeffH + ((size_t)(g * HID + nt * 16 + l15)) * HID + lh * 8);
  const char* wbY = (const char*)(Wob + (size_t)oy * HID + lh * 8);

  float c[4]; int mylen[4]; float biasRv[16];
#pragma unroll
  for (int r = 0; r < 4; ++r) {
    c[r] = c0g[(size_t)(bD0 + r) * HID + j];
    mylen[r] = len[bD0 + r];
    size_t bi = (size_t)(bD0 + r) * G4 + nt * 16 + l15;
#pragma unroll
    for (int g = 0; g < 4; ++g) biasRv[r * 4 + g] = biasR[bi + (size_t)g * HID];
  }

  // staging-slot addressing: slot s = i*256+tid -> row s>>5 (0..63), 16B-quad s&31
  // LDS write addr: row*512 + ((quad*16) ^ ((row&7)<<4))  [T2 involution]
  const _Float16* cb0[8];
  int rc8[8];
#pragma unroll
  for (int i = 0; i < 8; ++i) {
    int s = i * 256 + tid;
    int r = s >> 5, cc = s & 31;
    cb0[i] = hF + ((size_t)(mt * 64 + r) * HID + cc * 8);
    rc8[i] = r * 512 + ((cc * 16) ^ ((r & 7) << 4));
  }
  const int rdbase = rowA * 512;
  const int rsw = (rowA & 7) << 4;
  _Float16* hb0[4];
#pragma unroll
  for (int r = 0; r < 4; ++r) hb0[r] = hF + ((size_t)(bD0 + r) * HID + j);

  unsigned* const myarr = bar + (size_t)(mt * 8 + xcd) * 64;   // 256B-spaced lines

  f32x4 accM[4], accyM;
  f16x8 pfb[4][8];

  for (int t = 0; t < TLEN; ++t) {
    const size_t parin  = (size_t)(t & 1) * (BB * HID);
    const size_t parout = (size_t)((t + 1) & 1) * (BB * HID);

    auto issue = [&](int K) {
#pragma unroll
      for (int i = 0; i < 8; ++i)
        pfb[K][i] = ldg_sc_h8(cb0[i] + parin + K * 256);
    };
    auto dswr = [&](int K) {
      char* Bb = lds + K * 32768;
#pragma unroll
      for (int i = 0; i < 8; ++i)
        *(f16x8*)(Bb + rc8[i]) = pfb[K][i];
    };
    auto comp = [&](int K) {
      const char* Bb = lds + K * 32768;
#pragma unroll
      for (int kc = 0; kc < 8; ++kc) {
        f16x8 aH = *(const f16x8*)(Bb + rdbase + ((kc * 64 + lh * 16) ^ rsw));
        const int wo = K * 512 + kc * 64;
#pragma unroll
        for (int g = 0; g < 4; ++g) {
          f16x8 wH = *(const f16x8*)(wb[g] + wo);
          accM[g] = MFMA16(aH, wH, accM[g]);
        }
        if (doy) {
          f16x8 wy = *(const f16x8*)(wbY + wo);
          accyM = MFMA16(aH, wy, accyM);
        }
      }
    };

    // full-step prefetch: all 32 loads in flight (MALL latency paid once)
    issue(0); issue(1); issue(2); issue(3);

    // accumulator init (overlaps load latency)
#pragma unroll
    for (int r = 0; r < 4; ++r) {
#pragma unroll
      for (int g = 0; g < 4; ++g) accM[g][r] = biasRv[r * 4 + g];
      accyM[r] = bo;
    }
    if (t == 0) {
#pragma unroll
      for (int r = 0; r < 4; ++r) {
        size_t bi = (size_t)(bD0 + r) * G4 + nt * 16 + l15;
#pragma unroll
        for (int g = 0; g < 4; ++g) accM[g][r] = biasS[bi + (size_t)g * HID];
      }
    }

    // staged drain -> LDS; ONE barrier; 4 uninterrupted comp phases
    waitvm<24>(); dswr(0);
    waitvm<16>(); dswr(1);
    waitvm<8>();  dswr(2);
    waitvm<0>();  dswr(3);
    LDSBAR();
    comp(0); comp(1); comp(2); comp(3);

    // LSTM cell (fp32), f16 h_{t+1} store
#pragma unroll
    for (int r = 0; r < 4; ++r) {
      float ig = fsig(accM[0][r]);
      float fg = fsig(accM[1][r]);
      float gg = ftanh_(accM[2][r]);
      float og = fsig(accM[3][r]);
      float cn = fg * c[r] + ig * gg;
      c[r] = cn;
      float hn = og * ftanh_(cn);
      stg_sc_h(hb0[r] + parout, (_Float16)hn);
    }

    // drain h stores, publish, THEN y-stores (off the producer->consumer edge)
    asm volatile("s_waitcnt vmcnt(0)" ::: "memory");
    __syncthreads();
    if (tid == 0)
      __hip_atomic_fetch_add(myarr, 1u, __ATOMIC_RELAXED, __HIP_MEMORY_SCOPE_AGENT);
    if (doy && t > 0) {
      int tb = t - 1;
#pragma unroll
      for (int r = 0; r < 4; ++r) {
        float v = (tb < mylen[r]) ? accyM[r] : 0.0f;
        stg_sc_f32(out + ((size_t)(bD0 + r) * TLEN + tb) * OUTD + oy, v);
      }
    }
    if (tid < 64 && (t < TLEN - 1 || doy)) {
      unsigned tgt = 8u * (unsigned)(t + 1);
      long guard = 0;
      for (;;) {
        unsigned v = tgt;
        if (tid < 8)
          v = __hip_atomic_load(bar + (size_t)(mt * 8 + tid) * 64,
                                __ATOMIC_RELAXED, __HIP_MEMORY_SCOPE_AGENT);
        if (__ballot(v >= tgt) == ~0ull) break;
        if (++guard > 2000000L) break;   // tripwire: fail visibly, don't hang
        __builtin_amdgcn_s_sleep(2);
      }
    }
    __syncthreads();
  }

  // epilogue: y_{511} = Wout*h_512 + bout   (h_512 in parity-0 buffer)
  if (doy) {
    f32x4 aM;
#pragma unroll
    for (int r = 0; r < 4; ++r) aM[r] = bo;
    const _Float16* ebase = hF + (size_t)(mt * 64 + rowA) * HID + lh * 8;
    for (int b = 0; b < 8; ++b) {
      f16x8 e[4];
#pragma unroll
      for (int kc = 0; kc < 4; ++kc)
        e[kc] = ldg_sc_h8(ebase + b * 128 + kc * 32);
      asm volatile("s_waitcnt vmcnt(0)" ::: "memory");
      __builtin_amdgcn_sched_barrier(0);
#pragma unroll
      for (int kc = 0; kc < 4; ++kc) {
        f16x8 wy = *(const f16x8*)(wbY + b * 256 + kc * 64);
        aM = MFMA16(e[kc], wy, aM);
      }
    }
#pragma unroll
    for (int r = 0; r < 4; ++r) {
      float v = ((TLEN - 1) < mylen[r]) ? aM[r] : 0.0f;
      stg_sc_f32(out + ((size_t)(bD0 + r) * TLEN + (TLEN - 1)) * OUTD + oy, v);
    }
  }
}

// ---------------- host ----------------

extern "C" void kernel_launch(void* const* d_in, const int* in_sizes, int n_in,
                              void* d_out, int out_size, void* d_ws, size_t ws_size,
                              hipStream_t stream)
{
  const float* lat  = (const float*)d_in[0];
  const float* cond = (const float*)d_in[1];
  const int*   len  = (const int*)d_in[2];
  const float* Wh   = (const float*)d_in[3];
  const float* bh   = (const float*)d_in[4];
  const float* Wc   = (const float*)d_in[5];
  const float* bc   = (const float*)d_in[6];
  const float* Ws   = (const float*)d_in[7];
  const float* bs   = (const float*)d_in[8];
  const float* Wih  = (const float*)d_in[9];
  const float* Whh  = (const float*)d_in[10];
  const float* bih  = (const float*)d_in[11];
  const float* bhh  = (const float*)d_in[12];
  const float* Wout = (const float*)d_in[13];
  const float* bout = (const float*)d_in[14];
  float* out = (float*)d_out;

  char* ws = (char*)d_ws;
  size_t off = 0;
  auto alloc = [&](size_t bytes) -> void* {
    void* p = ws + off;
    off += (bytes + 255) & ~(size_t)255;
    return p;
  };
  _Float16* hF    = (_Float16*)alloc((size_t)2 * BB * HID * 2);   // single f16 plane
  float*    c0    = (float*)alloc((size_t)BB * HID * 4);
  float*    h0    = (float*)alloc((size_t)BB * HID * 4);
  float*    x0    = (float*)alloc((size_t)BB * OUTD * 4);
  float*    dxy   = (float*)alloc((size_t)BB * OUTD * 4);
  _Float16* Wob   = (_Float16*)alloc((size_t)OUTD * HID * 2);
  _Float16* WeffH = (_Float16*)alloc((size_t)G4 * HID * 2);
  float*    biasR = (float*)alloc((size_t)BB * G4 * 4);
  float*    biasS = (float*)alloc((size_t)BB * G4 * 4);
  unsigned* bar   = (unsigned*)alloc(4 * 8 * 64 * 4);             // 32 lines, 256B apart
  if (off > ws_size) return;

  hipMemsetAsync(bar, 0, 4 * 8 * 64 * 4, stream);

  prep_init<<<dim3(9, 32),   256, 0, stream>>>(lat, Wh, bh, Wc, bc, Ws, bs, h0, hF, c0, x0);
  prep_weff<<<dim3(4, 256),  256, 0, stream>>>(Whh, Wih, Wout, WeffH);
  prep_wob <<<dim3(512),     256, 0, stream>>>(Wout, Wob);
  prep_d   <<<dim3(128),     256, 0, stream>>>(h0, Wout, bout, x0, dxy);
  prep_bias<<<dim3(16, 32),  256, 0, stream>>>(cond, Wih, bih, bhh, bout, dxy, biasR, biasS);
  lstm_main<<<dim3(256),     256, 0, stream>>>(hF, c0, biasR, biasS, WeffH, Wob, bout, len, out, bar);
}